// Round 14
// baseline (208.368 us; speedup 1.0000x reference)
//
#include <hip/hip_runtime.h>
#include <math.h>

// Problem dims (fixed by reference)
#define BB   64
#define NN   8192
#define FF   128
#define HH   512
#define GG   2048
#define EE   256
#define VV   10000
#define EPSF 1e-6f

// Workspace layout (floats)
static constexpr size_t OFF_XT    = 0;                        // 768*64    = 49152
static constexpr size_t OFF_GPART = 49152;                    // 2*2048*64 = 262144
static constexpr size_t OFF_H2T   = 311296;                   // 512*64    = 32768
static constexpr size_t OFF_HPART = 344064;                   // 2*524*64  = 67072
static constexpr size_t OFF_PAR   = 411136;                   // 64*544    = 34816
static constexpr size_t OFF_ZW    = 445952;                   // 524288
static constexpr size_t OFF_Q4    = 970240;                   // 4*524288 = 2097152 (16B aligned)
static constexpr size_t OFF_Q1    = 3067392;                  // 524288
static constexpr size_t OFF_WR    = 3591680;                  // 524288
static constexpr size_t OFF_WRWW  = 4115968;                  // 524288
static constexpr size_t OFF_PT    = 4640256;                  // 2048*256 = 524288
static constexpr size_t OFF_T3    = 5164544;                  // 64
static constexpr size_t OFF_RVEC  = 5164608;                  // 8192
// total ~ 20.7 MB

__device__ __forceinline__ float sigmoidf_(float x){ return 1.f/(1.f + __expf(-x)); }
__device__ __forceinline__ float softplusf_(float x){ return (x > 20.f) ? x : log1pf(__expf(x)); }

// ---------------- K0: gather Xt[k][b] = concat(emb[x[b]], h[b]) transposed --
__global__ __launch_bounds__(256) void gather_xt_kernel(
    const int* __restrict__ x, const float* __restrict__ h,
    const float* __restrict__ emb, float* __restrict__ Xt)
{
  const int idx = blockIdx.x*256 + threadIdx.x;    // 49152 = 768*64
  const int k = idx >> 6, b = idx & 63;
  float v = (k < EE) ? emb[(size_t)x[b]*EE + k] : h[(size_t)b*HH + (k - EE)];
  Xt[(size_t)k*64 + b] = v;
}

// ---------------- K1: gate partials; wave = 4 rows x K-half -----------------
// gpart[kc][j][b], kc plane stride 131072
__global__ __launch_bounds__(256) void lstm_gates_kernel(
    const float* __restrict__ Xt, const float* __restrict__ Wih,
    const float* __restrict__ Whh, float* __restrict__ gpart)
{
  const int tid = threadIdx.x;
  const int lane = tid & 63;
  const int gw = __builtin_amdgcn_readfirstlane(blockIdx.x*4 + (tid >> 6)); // 1024 waves
  const int jg = gw >> 1, kc = gw & 1;
  const int j0 = jg << 2;
  float a0=0.f, a1=0.f, a2=0.f, a3=0.f;
  if (kc == 0){
    const float* w0 = Wih + (size_t)(j0+0)*EE;
    const float* w1 = Wih + (size_t)(j0+1)*EE;
    const float* w2 = Wih + (size_t)(j0+2)*EE;
    const float* w3 = Wih + (size_t)(j0+3)*EE;
    #pragma unroll 4
    for (int k = 0; k < EE; ++k){
      const float xv = Xt[(size_t)k*64 + lane];
      a0 = fmaf(w0[k],xv,a0); a1 = fmaf(w1[k],xv,a1);
      a2 = fmaf(w2[k],xv,a2); a3 = fmaf(w3[k],xv,a3);
    }
    const float* v0 = Whh + (size_t)(j0+0)*HH;
    const float* v1 = Whh + (size_t)(j0+1)*HH;
    const float* v2 = Whh + (size_t)(j0+2)*HH;
    const float* v3 = Whh + (size_t)(j0+3)*HH;
    #pragma unroll 4
    for (int k = 0; k < 128; ++k){
      const float xv = Xt[(size_t)(EE+k)*64 + lane];
      a0 = fmaf(v0[k],xv,a0); a1 = fmaf(v1[k],xv,a1);
      a2 = fmaf(v2[k],xv,a2); a3 = fmaf(v3[k],xv,a3);
    }
  } else {
    const float* v0 = Whh + (size_t)(j0+0)*HH;
    const float* v1 = Whh + (size_t)(j0+1)*HH;
    const float* v2 = Whh + (size_t)(j0+2)*HH;
    const float* v3 = Whh + (size_t)(j0+3)*HH;
    #pragma unroll 4
    for (int k = 128; k < 512; ++k){
      const float xv = Xt[(size_t)(EE+k)*64 + lane];
      a0 = fmaf(v0[k],xv,a0); a1 = fmaf(v1[k],xv,a1);
      a2 = fmaf(v2[k],xv,a2); a3 = fmaf(v3[k],xv,a3);
    }
  }
  float* gp = gpart + (size_t)kc*131072 + (size_t)j0*64 + lane;
  gp[0] = a0; gp[64] = a1; gp[128] = a2; gp[192] = a3;
}

// ---------------- K2: reduce partials + LSTM activations -> h2t ------------
__global__ __launch_bounds__(256) void lstm_act_kernel(
    const float* __restrict__ gpart, const float* __restrict__ bih,
    const float* __restrict__ bhh, const float* __restrict__ c,
    float* __restrict__ h2t)
{
  const int idx = blockIdx.x*256 + threadIdx.x;   // 32768
  const int bb = idx & 63, hh = idx >> 6;
  #define GSUM(j) (gpart[(size_t)(j)*64+bb] + gpart[(size_t)131072+(size_t)(j)*64+bb] + bih[j] + bhh[j])
  const float gi = GSUM(hh);
  const float gf = GSUM(512+hh);
  const float gg = GSUM(1024+hh);
  const float go = GSUM(1536+hh);
  #undef GSUM
  const float c0 = c[(size_t)bb*HH + hh];
  const float c2 = sigmoidf_(gf)*c0 + sigmoidf_(gi)*tanhf(gg);
  h2t[(size_t)hh*64 + bb] = sigmoidf_(go)*tanhf(c2);
}

// ---------------- K3: head partials; wave = 4 rows x K-half -----------------
// hpart[kc][j][b], kc plane stride 33536
__global__ __launch_bounds__(256) void head_gemm_kernel(
    const float* __restrict__ h2t, const float* __restrict__ Ww,
    const float* __restrict__ Wr, float* __restrict__ hpart)
{
  const int tid = threadIdx.x;
  const int lane = tid & 63;
  const int gw = __builtin_amdgcn_readfirstlane(blockIdx.x*4 + (tid >> 6)); // 264 waves
  const int jg = gw >> 1, kc = gw & 1;
  if (jg >= 131) return;
  const int j0 = jg << 2;
  const float* w0 = (j0+0 < 390) ? (Ww + (size_t)(j0+0)*HH) : (Wr + (size_t)(j0+0-390)*HH);
  const float* w1 = (j0+1 < 390) ? (Ww + (size_t)(j0+1)*HH) : (Wr + (size_t)(j0+1-390)*HH);
  const float* w2 = (j0+2 < 390) ? (Ww + (size_t)(j0+2)*HH) : (Wr + (size_t)(j0+2-390)*HH);
  const float* w3 = (j0+3 < 390) ? (Ww + (size_t)(j0+3)*HH) : (Wr + (size_t)(j0+3-390)*HH);
  const int k0 = kc << 8;
  float a0=0.f, a1=0.f, a2=0.f, a3=0.f;
  #pragma unroll 4
  for (int k = k0; k < k0+256; ++k){
    const float xv = h2t[(size_t)k*64 + lane];
    a0 = fmaf(w0[k],xv,a0); a1 = fmaf(w1[k],xv,a1);
    a2 = fmaf(w2[k],xv,a2); a3 = fmaf(w3[k],xv,a3);
  }
  float* hp = hpart + (size_t)kc*33536 + (size_t)j0*64 + lane;
  hp[0] = a0; hp[64] = a1; hp[128] = a2; hp[192] = a3;
}

// ---------------- K4: interpret heads -> params[b] -------------------------
// params stride 544: [0:128] kwE, [128:256] krE, [256:384] a, [384:512] e,
// 512+: {beta_w,g_w,sw0,sw1,sw2,r_w, beta_r,g_r,sr0,sr1,sr2,r_r, nkw,nkr,C_akr,Ca2}
__global__ void interpret_kernel(const float* __restrict__ hp,
                                 const float* __restrict__ bw,
                                 const float* __restrict__ br,
                                 float* __restrict__ params)
{
  const int b = blockIdx.x, l = threadIdx.x;   // 64 threads
  float* P = params + (size_t)b*544;
  #define OC(j) (hp[(size_t)(j)*64+b] + hp[(size_t)33536+(size_t)(j)*64+b])
  float skw = 0.f, skr = 0.f, sakr = 0.f, sa2 = 0.f;
  #pragma unroll
  for (int f = l; f < 128; f += 64){
    float kwE = OC(f) + bw[f] + EPSF;
    float ee  = sigmoidf_(OC(134+f) + bw[134+f]);
    float aa  = OC(262+f) + bw[262+f];
    float krE = OC(390+f) + br[f] + EPSF;
    P[f] = kwE; P[128+f] = krE; P[256+f] = aa; P[384+f] = ee;
    skw = fmaf(kwE,kwE,skw); skr = fmaf(krE,krE,skr);
    sakr = fmaf(aa,krE,sakr); sa2 = fmaf(aa,aa,sa2);
  }
  #pragma unroll
  for (int m = 32; m >= 1; m >>= 1){
    skw += __shfl_xor(skw,m); skr += __shfl_xor(skr,m);
    sakr += __shfl_xor(sakr,m); sa2 += __shfl_xor(sa2,m);
  }
  if (l == 0){
    P[512+0] = softplusf_(OC(128) + bw[128]);
    P[512+1] = sigmoidf_(OC(129) + bw[129]);
    {
      float x0 = OC(130)+bw[130], x1 = OC(131)+bw[131], x2 = OC(132)+bw[132];
      float mm = fmaxf(x0, fmaxf(x1, x2));
      float e0 = __expf(x0-mm), e1 = __expf(x1-mm), e2 = __expf(x2-mm);
      float s = e0+e1+e2;
      P[512+2] = e0/s; P[512+3] = e1/s; P[512+4] = e2/s;
    }
    P[512+5] = 1.f + softplusf_(OC(133) + bw[133]);
    P[512+6] = softplusf_(OC(518) + br[128]);
    P[512+7] = sigmoidf_(OC(519) + br[129]);
    {
      float x0 = OC(520)+br[130], x1 = OC(521)+br[131], x2 = OC(522)+br[132];
      float mm = fmaxf(x0, fmaxf(x1, x2));
      float e0 = __expf(x0-mm), e1 = __expf(x1-mm), e2 = __expf(x2-mm);
      float s = e0+e1+e2;
      P[512+8] = e0/s; P[512+9] = e1/s; P[512+10] = e2/s;
    }
    P[512+11] = 1.f + softplusf_(OC(523) + br[133]);
    P[512+12] = sqrtf(skw); P[512+13] = sqrtf(skr);
    P[512+14] = sakr;       P[512+15] = sa2;
  }
  #undef OC
}

// ---------------- K5: big pass A — per-row scalars over bank ---------------
// per row: zw = beta_w*cos-sim ; q4 = {S2, S3, C_akr-S4, S5-S6} ; q1 = Ca2-2S7+S8
// NEW (single change this round): 16 lanes/row x 8 feats (was 8x16) ->
// param fragments 64->32 VGPR, staged data 32->16 VGPR. Total ~60-70 VGPR,
// aiming to cross the <=64 occupancy step (4 -> 8 waves/SIMD) for more
// outstanding L2/HBM read parallelism. Dense per-instruction coverage kept:
// lane f, load i reads floats [64i+4f, 64i+4f+4). Reduction = 4 shfl levels.
__global__ __launch_bounds__(256) void pass_a_kernel(
    const float* __restrict__ bank, const float* __restrict__ params,
    float* __restrict__ zw, float4* __restrict__ q4, float* __restrict__ q1)
{
  const int blk = blockIdx.x;            // 2048 = 64 b * 32 chunks
  const int b = blk >> 5, chunk = blk & 31;
  const int tid = threadIdx.x;
  const int wv = tid >> 6, lane = tid & 63;
  const int fslot = lane & 15, rsub = lane >> 4;   // 16 lanes per row, 4 rows/wave
  const float* P = params + (size_t)b*544;
  float kw[8], kr[8], av[8], ev[8];
  #pragma unroll
  for (int i = 0; i < 2; ++i){
    #pragma unroll
    for (int j = 0; j < 4; ++j){
      const int idx = 64*i + 4*fslot + j;
      kw[4*i+j] = P[idx];     kr[4*i+j] = P[128+idx];
      av[4*i+j] = P[256+idx]; ev[4*i+j] = P[384+idx];
    }
  }
  const float beta_w = P[512+0], nkw = P[512+12];
  const float C_akr = P[512+14], Ca2 = P[512+15];
  const int eoff = 4*fslot;   // float offset of load i: 64*i + eoff

  for (int it = 0; it < 16; it += 2){
    const int n0 = (chunk << 8) + (it << 4) + (wv << 2) + rsub;
    const size_t rowA = (size_t)b*NN + n0;
    const size_t rowB = rowA + 16;
    const float* pA = bank + rowA*FF + eoff;
    const float* pB = bank + rowB*FF + eoff;
    float va[8], vb[8];
    *reinterpret_cast<float4*>(&va[0]) = *reinterpret_cast<const float4*>(pA);
    *reinterpret_cast<float4*>(&va[4]) = *reinterpret_cast<const float4*>(pA + 64);
    *reinterpret_cast<float4*>(&vb[0]) = *reinterpret_cast<const float4*>(pB);
    *reinterpret_cast<float4*>(&vb[4]) = *reinterpret_cast<const float4*>(pB + 64);

    #pragma unroll
    for (int half = 0; half < 2; ++half){
      const float* mv = (half == 0) ? va : vb;
      const size_t row = (half == 0) ? rowA : rowB;
      float s1=0.f,s2=0.f,s3=0.f,s4=0.f,s5=0.f,s6=0.f,s7=0.f,s8=0.f;
      #pragma unroll
      for (int i = 0; i < 8; ++i){
        const float m = mv[i], u = m + EPSF, em = ev[i]*m;
        s1 = fmaf(u,kw[i],s1);  s2 = fmaf(u,u,s2);
        s3 = fmaf(u,kr[i],s3);  s4 = fmaf(em,kr[i],s4);
        s5 = fmaf(u,av[i],s5);  s6 = fmaf(u,em,s6);
        s7 = fmaf(av[i],em,s7); s8 = fmaf(em,em,s8);
      }
      #pragma unroll
      for (int mm = 1; mm < 16; mm <<= 1){
        s1 += __shfl_xor(s1,mm); s2 += __shfl_xor(s2,mm);
        s3 += __shfl_xor(s3,mm); s4 += __shfl_xor(s4,mm);
        s5 += __shfl_xor(s5,mm); s6 += __shfl_xor(s6,mm);
        s7 += __shfl_xor(s7,mm); s8 += __shfl_xor(s8,mm);
      }
      if (fslot == 0){
        const float sim = s1 / fmaxf(sqrtf(s2)*nkw, 1e-8f);
        zw[row] = beta_w * sim;
        q4[row] = make_float4(s2, s3, C_akr - s4, s5 - s6);
        q1[row] = Ca2 - 2.f*s7 + s8;
      }
    }
  }
}

// ---------------- 2-sync block reductions for K6 (1024 thr = 16 waves) -----
__device__ __forceinline__ float blockMaxF(float v, float* red, int tid){
  #pragma unroll
  for (int m = 32; m >= 1; m >>= 1) v = fmaxf(v, __shfl_xor(v,m));
  if ((tid & 63) == 0) red[tid >> 6] = v;
  __syncthreads();
  if (tid < 64){
    float x = (tid < 16) ? red[tid] : -1e30f;
    #pragma unroll
    for (int m = 8; m >= 1; m >>= 1) x = fmaxf(x, __shfl_xor(x,m));
    if (tid == 0) red[16] = x;
  }
  __syncthreads();
  return red[16];
}
__device__ __forceinline__ float blockSumF(float v, float* red, int tid){
  #pragma unroll
  for (int m = 32; m >= 1; m >>= 1) v += __shfl_xor(v,m);
  if ((tid & 63) == 0) red[tid >> 6] = v;
  __syncthreads();
  if (tid < 64){
    float x = (tid < 16) ? red[tid] : 0.f;
    #pragma unroll
    for (int m = 8; m >= 1; m >>= 1) x += __shfl_xor(x,m);
    if (tid == 0) red[16] = x;
  }
  __syncthreads();
  return red[16];
}

// ---------------- K6: per-batch softmax/conv/sharpen pipeline x2 -----------
// All global loads hoisted to entry; sharpen results kept in registers.
__global__ __launch_bounds__(1024) void head_pipeline_kernel(
    const float* __restrict__ zw, const float4* __restrict__ q4,
    const float* __restrict__ q1,
    const float* __restrict__ w_write, const float* __restrict__ w_read,
    const float* __restrict__ params,
    float* __restrict__ wrg, float* __restrict__ wrwwg, float* __restrict__ T3g)
{
  __shared__ float wa[NN];
  __shared__ float red[20];
  const int b = blockIdx.x;
  const int tid = threadIdx.x;
  const float* P = params + (size_t)b*544 + 512;
  const float g_w = P[1], sw0 = P[2], sw1 = P[3], sw2 = P[4], r_w = P[5];
  const float beta_r = P[6], g_r = P[7], sr0 = P[8], sr1 = P[9], sr2 = P[10], r_r = P[11];
  const float nkr = P[13];
  const size_t base = (size_t)b*NN;

  // ---- hoist ALL global loads (latency paid once, overlapped) ----
  float  zv[8], q1v[8], wwr[8], wrd[8];
  float4 qv[8];
  #pragma unroll
  for (int i = 0; i < 8; ++i){ int n = tid + (i<<10); zv[i]  = zw[base+n]; }
  #pragma unroll
  for (int i = 0; i < 8; ++i){ int n = tid + (i<<10); qv[i]  = q4[base+n]; }
  #pragma unroll
  for (int i = 0; i < 8; ++i){ int n = tid + (i<<10); q1v[i] = q1[base+n]; }
  #pragma unroll
  for (int i = 0; i < 8; ++i){ int n = tid + (i<<10); wwr[i] = w_write[base+n]; }
  #pragma unroll
  for (int i = 0; i < 8; ++i){ int n = tid + (i<<10); wrd[i] = w_read[base+n]; }

  float cv[8], wwv[8];

  // ======== write head ========
  float lm = -1e30f;
  #pragma unroll
  for (int i = 0; i < 8; ++i) lm = fmaxf(lm, zv[i]);
  float M = blockMaxF(lm, red, tid);
  float ls = 0.f;
  #pragma unroll
  for (int i = 0; i < 8; ++i){ zv[i] = __expf(zv[i]-M); ls += zv[i]; }
  float S = blockSumF(ls, red, tid);
  const float invS = 1.f/S;
  #pragma unroll
  for (int i = 0; i < 8; ++i){ int n = tid + (i<<10); wa[n] = zv[i]*invS + (1.f-g_w)*wwr[i]; }
  __syncthreads();
  #pragma unroll
  for (int i = 0; i < 8; ++i){ int n = tid + (i<<10);
    cv[i] = sw0*wa[(n+NN-1)&(NN-1)] + sw1*wa[n] + sw2*wa[(n+1)&(NN-1)]; }
  __syncthreads();
  float lp = 0.f;
  #pragma unroll
  for (int i = 0; i < 8; ++i){ cv[i] = __expf(r_w*__logf(cv[i])); lp += cv[i]; }
  float Sp = blockSumF(lp, red, tid);
  float inv = 1.f/(Sp + EPSF);
  #pragma unroll
  for (int i = 0; i < 8; ++i) wwv[i] = cv[i]*inv;

  // ======== read head (bank2 stats reconstructed from qv/q1v + ww) ========
  lm = -1e30f;
  #pragma unroll
  for (int i = 0; i < 8; ++i){
    const float ww = wwv[i];
    const float num = qv[i].y + ww*qv[i].z;
    const float d2  = qv[i].x + 2.f*ww*qv[i].w + ww*ww*q1v[i];
    const float den = sqrtf(d2)*nkr;
    zv[i] = beta_r * (num / fmaxf(den, 1e-8f));
    lm = fmaxf(lm, zv[i]);
  }
  M = blockMaxF(lm, red, tid);
  ls = 0.f;
  #pragma unroll
  for (int i = 0; i < 8; ++i){ zv[i] = __expf(zv[i]-M); ls += zv[i]; }
  S = blockSumF(ls, red, tid);
  const float invS2 = 1.f/S;
  #pragma unroll
  for (int i = 0; i < 8; ++i){ int n = tid + (i<<10); wa[n] = zv[i]*invS2 + (1.f-g_r)*wrd[i]; }
  __syncthreads();
  #pragma unroll
  for (int i = 0; i < 8; ++i){ int n = tid + (i<<10);
    cv[i] = sr0*wa[(n+NN-1)&(NN-1)] + sr1*wa[n] + sr2*wa[(n+1)&(NN-1)]; }
  __syncthreads();
  float lp2 = 0.f;
  #pragma unroll
  for (int i = 0; i < 8; ++i){ cv[i] = __expf(r_r*__logf(cv[i])); lp2 += cv[i]; }
  float Sp2 = blockSumF(lp2, red, tid);
  inv = 1.f/(Sp2 + EPSF);
  float t3 = 0.f;
  #pragma unroll
  for (int i = 0; i < 8; ++i){
    int n = tid + (i<<10);
    const float wr_ = cv[i]*inv;
    wrg[base+n] = wr_;
    const float xx = wr_*wwv[i];
    wrwwg[base+n] = xx;
    t3 += xx;
  }
  float T3 = blockSumF(t3, red, tid);
  if (tid == 0) T3g[b] = T3;
}

// ---------------- K7: big pass D — weighted reductions over bank -----------
// REVERSED traversal (L3-resident tail first); unrolled x8 for MLP.
__global__ __launch_bounds__(256) void pass_d_kernel(
    const float* __restrict__ bank, const float* __restrict__ wrg,
    const float* __restrict__ wrwwg, float* __restrict__ pT)
{
  const int blk = 2047 - blockIdx.x;    // 2048 = 64 b * 32 chunks, reversed
  const int b = blk >> 5, chunk = blk & 31;
  const int tid = threadIdx.x;
  const int st = tid >> 5, li = tid & 31;   // 8 row-streams, 32 f4 each
  float4 a1 = make_float4(0.f,0.f,0.f,0.f);
  float4 a2 = make_float4(0.f,0.f,0.f,0.f);
  for (int it = 24; it >= 0; it -= 8){
    float w1v[8], w2v[8];
    float4 mv[8];
    #pragma unroll
    for (int u = 0; u < 8; ++u){
      const int n = (chunk << 8) + ((it+u) << 3) + st;
      const size_t row = (size_t)b*NN + n;
      w1v[u] = wrg[row];
      w2v[u] = wrwwg[row];
      mv[u] = reinterpret_cast<const float4*>(bank + row*FF)[li];
    }
    #pragma unroll
    for (int u = 0; u < 8; ++u){
      a1.x = fmaf(w1v[u],mv[u].x,a1.x); a1.y = fmaf(w1v[u],mv[u].y,a1.y);
      a1.z = fmaf(w1v[u],mv[u].z,a1.z); a1.w = fmaf(w1v[u],mv[u].w,a1.w);
      a2.x = fmaf(w2v[u],mv[u].x,a2.x); a2.y = fmaf(w2v[u],mv[u].y,a2.y);
      a2.z = fmaf(w2v[u],mv[u].z,a2.z); a2.w = fmaf(w2v[u],mv[u].w,a2.w);
    }
  }
  __shared__ float lds[8*256];
  *reinterpret_cast<float4*>(&lds[st*256 + li*4]) = a1;
  *reinterpret_cast<float4*>(&lds[st*256 + 128 + li*4]) = a2;
  __syncthreads();
  float s = 0.f;
  #pragma unroll
  for (int k = 0; k < 8; ++k) s += lds[k*256 + tid];
  pT[(size_t)blk*256 + tid] = s;
}

// ---------------- K7b: reduce partials -> rvec ------------------------------
__global__ __launch_bounds__(256) void rvec_kernel(
    const float* __restrict__ pT, const float* __restrict__ params,
    const float* __restrict__ T3g, float* __restrict__ rvec)
{
  const int gid = blockIdx.x*256 + threadIdx.x;   // 8192
  const int b = gid >> 7, f = gid & 127;
  float t1 = 0.f, t2 = 0.f;
  for (int cc = 0; cc < 32; ++cc){
    const float* p = pT + (size_t)((b<<5) + cc)*256;
    t1 += p[f]; t2 += p[128+f];
  }
  const float* P = params + (size_t)b*544;
  rvec[gid] = t1 - P[384+f]*t2 + P[256+f]*T3g[b];
}

// ---------------- K8: out = rvec @ W_out^T + b_out --------------------------
__global__ __launch_bounds__(256) void out_gemm_kernel(
    const float* __restrict__ rvec, const float* __restrict__ Wout,
    const float* __restrict__ bout, float* __restrict__ out)
{
  const int tid = threadIdx.x;
  const int wv = __builtin_amdgcn_readfirstlane(tid >> 6);
  const int lane = tid & 63;     // lane = batch
  const int j0 = blockIdx.x*32 + wv*8;
  float acc[8];
  #pragma unroll
  for (int jj = 0; jj < 8; ++jj){ int j = j0 + jj; acc[jj] = (j < VV) ? bout[j] : 0.f; }
  for (int fc = 0; fc < 128; fc += 32){
    float rv[32];
    #pragma unroll
    for (int i = 0; i < 32; ++i) rv[i] = rvec[lane*128 + fc + i];
    #pragma unroll
    for (int jj = 0; jj < 8; ++jj){
      const int j = j0 + jj;
      if (j < VV){
        const float* w = Wout + (size_t)j*128 + fc;
        #pragma unroll
        for (int i = 0; i < 32; ++i) acc[jj] = fmaf(w[i], rv[i], acc[jj]);
      }
    }
  }
  #pragma unroll
  for (int jj = 0; jj < 8; ++jj){
    int j = j0 + jj;
    if (j < VV) out[(size_t)lane*VV + j] = acc[jj];
  }
}

// ---------------------------------------------------------------------------
extern "C" void kernel_launch(void* const* d_in, const int* in_sizes, int n_in,
                              void* d_out, int out_size, void* d_ws, size_t ws_size,
                              hipStream_t stream)
{
  const int*   x       = (const int*)  d_in[0];
  const float* h       = (const float*)d_in[1];
  const float* c       = (const float*)d_in[2];
  const float* w_read  = (const float*)d_in[3];
  const float* w_write = (const float*)d_in[4];
  const float* bank    = (const float*)d_in[5];
  const float* emb     = (const float*)d_in[6];
  const float* Wih     = (const float*)d_in[7];
  const float* bih     = (const float*)d_in[8];
  const float* Whh     = (const float*)d_in[9];
  const float* bhh     = (const float*)d_in[10];
  const float* Wr      = (const float*)d_in[11];
  const float* br      = (const float*)d_in[12];
  const float* Ww      = (const float*)d_in[13];
  const float* bw      = (const float*)d_in[14];
  const float* Wout    = (const float*)d_in[15];
  const float* bout    = (const float*)d_in[16];
  float* out = (float*)d_out;
  float* ws  = (float*)d_ws;

  float* Xt    = ws + OFF_XT;
  float* gpart = ws + OFF_GPART;
  float* h2t   = ws + OFF_H2T;
  float* hpart = ws + OFF_HPART;
  float* par   = ws + OFF_PAR;
  float* zwp   = ws + OFF_ZW;
  float4* q4p  = reinterpret_cast<float4*>(ws + OFF_Q4);
  float* q1p   = ws + OFF_Q1;
  float* wrp   = ws + OFF_WR;
  float* wrwwp = ws + OFF_WRWW;
  float* pTp   = ws + OFF_PT;
  float* T3p   = ws + OFF_T3;
  float* rvp   = ws + OFF_RVEC;

  hipLaunchKernelGGL(gather_xt_kernel,     dim3(192),  dim3(256), 0, stream, x, h, emb, Xt);
  hipLaunchKernelGGL(lstm_gates_kernel,    dim3(256),  dim3(256), 0, stream, Xt, Wih, Whh, gpart);
  hipLaunchKernelGGL(lstm_act_kernel,      dim3(128),  dim3(256), 0, stream, gpart, bih, bhh, c, h2t);
  hipLaunchKernelGGL(head_gemm_kernel,     dim3(66),   dim3(256), 0, stream, h2t, Ww, Wr, hpart);
  hipLaunchKernelGGL(interpret_kernel,     dim3(64),   dim3(64),  0, stream, hpart, bw, br, par);
  hipLaunchKernelGGL(pass_a_kernel,        dim3(2048), dim3(256), 0, stream, bank, par, zwp, q4p, q1p);
  hipLaunchKernelGGL(head_pipeline_kernel, dim3(64),   dim3(1024),0, stream, zwp, q4p, q1p, w_write, w_read, par, wrp, wrwwp, T3p);
  hipLaunchKernelGGL(pass_d_kernel,        dim3(2048), dim3(256), 0, stream, bank, wrp, wrwwp, pTp);
  hipLaunchKernelGGL(rvec_kernel,          dim3(32),   dim3(256), 0, stream, pTp, par, T3p, rvp);
  hipLaunchKernelGGL(out_gemm_kernel,      dim3(313),  dim3(256), 0, stream, rvp, Wout, bout, out);
}

// Round 15
// 196.092 us; speedup vs baseline: 1.0626x; 1.0626x over previous
//
#include <hip/hip_runtime.h>
#include <math.h>

// Problem dims (fixed by reference)
#define BB   64
#define NN   8192
#define FF   128
#define HH   512
#define GG   2048
#define EE   256
#define VV   10000
#define EPSF 1e-6f

// Workspace layout (floats)
static constexpr size_t OFF_XT    = 0;                        // 768*64    = 49152
static constexpr size_t OFF_GPART = 49152;                    // 2*2048*64 = 262144
static constexpr size_t OFF_H2T   = 311296;                   // 512*64    = 32768
static constexpr size_t OFF_HPART = 344064;                   // 2*524*64  = 67072
static constexpr size_t OFF_PAR   = 411136;                   // 64*544    = 34816
static constexpr size_t OFF_ZW    = 445952;                   // 524288
static constexpr size_t OFF_Q4    = 970240;                   // 4*524288 = 2097152 (16B aligned)
static constexpr size_t OFF_Q1    = 3067392;                  // 524288
static constexpr size_t OFF_WR    = 3591680;                  // 524288
static constexpr size_t OFF_WRWW  = 4115968;                  // 524288
static constexpr size_t OFF_PT    = 4640256;                  // 2048*256 = 524288
static constexpr size_t OFF_T3    = 5164544;                  // 64
static constexpr size_t OFF_RVEC  = 5164608;                  // 8192
// total ~ 20.7 MB

__device__ __forceinline__ float sigmoidf_(float x){ return 1.f/(1.f + __expf(-x)); }
__device__ __forceinline__ float softplusf_(float x){ return (x > 20.f) ? x : log1pf(__expf(x)); }

// ---------------- K0: gather Xt[k][b] = concat(emb[x[b]], h[b]) transposed --
__global__ __launch_bounds__(256) void gather_xt_kernel(
    const int* __restrict__ x, const float* __restrict__ h,
    const float* __restrict__ emb, float* __restrict__ Xt)
{
  const int idx = blockIdx.x*256 + threadIdx.x;    // 49152 = 768*64
  const int k = idx >> 6, b = idx & 63;
  float v = (k < EE) ? emb[(size_t)x[b]*EE + k] : h[(size_t)b*HH + (k - EE)];
  Xt[(size_t)k*64 + b] = v;
}

// ---------------- K1: gate partials; wave = 4 rows x K-half -----------------
// gpart[kc][j][b], kc plane stride 131072
__global__ __launch_bounds__(256) void lstm_gates_kernel(
    const float* __restrict__ Xt, const float* __restrict__ Wih,
    const float* __restrict__ Whh, float* __restrict__ gpart)
{
  const int tid = threadIdx.x;
  const int lane = tid & 63;
  const int gw = __builtin_amdgcn_readfirstlane(blockIdx.x*4 + (tid >> 6)); // 1024 waves
  const int jg = gw >> 1, kc = gw & 1;
  const int j0 = jg << 2;
  float a0=0.f, a1=0.f, a2=0.f, a3=0.f;
  if (kc == 0){
    const float* w0 = Wih + (size_t)(j0+0)*EE;
    const float* w1 = Wih + (size_t)(j0+1)*EE;
    const float* w2 = Wih + (size_t)(j0+2)*EE;
    const float* w3 = Wih + (size_t)(j0+3)*EE;
    #pragma unroll 4
    for (int k = 0; k < EE; ++k){
      const float xv = Xt[(size_t)k*64 + lane];
      a0 = fmaf(w0[k],xv,a0); a1 = fmaf(w1[k],xv,a1);
      a2 = fmaf(w2[k],xv,a2); a3 = fmaf(w3[k],xv,a3);
    }
    const float* v0 = Whh + (size_t)(j0+0)*HH;
    const float* v1 = Whh + (size_t)(j0+1)*HH;
    const float* v2 = Whh + (size_t)(j0+2)*HH;
    const float* v3 = Whh + (size_t)(j0+3)*HH;
    #pragma unroll 4
    for (int k = 0; k < 128; ++k){
      const float xv = Xt[(size_t)(EE+k)*64 + lane];
      a0 = fmaf(v0[k],xv,a0); a1 = fmaf(v1[k],xv,a1);
      a2 = fmaf(v2[k],xv,a2); a3 = fmaf(v3[k],xv,a3);
    }
  } else {
    const float* v0 = Whh + (size_t)(j0+0)*HH;
    const float* v1 = Whh + (size_t)(j0+1)*HH;
    const float* v2 = Whh + (size_t)(j0+2)*HH;
    const float* v3 = Whh + (size_t)(j0+3)*HH;
    #pragma unroll 4
    for (int k = 128; k < 512; ++k){
      const float xv = Xt[(size_t)(EE+k)*64 + lane];
      a0 = fmaf(v0[k],xv,a0); a1 = fmaf(v1[k],xv,a1);
      a2 = fmaf(v2[k],xv,a2); a3 = fmaf(v3[k],xv,a3);
    }
  }
  float* gp = gpart + (size_t)kc*131072 + (size_t)j0*64 + lane;
  gp[0] = a0; gp[64] = a1; gp[128] = a2; gp[192] = a3;
}

// ---------------- K2: reduce partials + LSTM activations -> h2t ------------
__global__ __launch_bounds__(256) void lstm_act_kernel(
    const float* __restrict__ gpart, const float* __restrict__ bih,
    const float* __restrict__ bhh, const float* __restrict__ c,
    float* __restrict__ h2t)
{
  const int idx = blockIdx.x*256 + threadIdx.x;   // 32768
  const int bb = idx & 63, hh = idx >> 6;
  #define GSUM(j) (gpart[(size_t)(j)*64+bb] + gpart[(size_t)131072+(size_t)(j)*64+bb] + bih[j] + bhh[j])
  const float gi = GSUM(hh);
  const float gf = GSUM(512+hh);
  const float gg = GSUM(1024+hh);
  const float go = GSUM(1536+hh);
  #undef GSUM
  const float c0 = c[(size_t)bb*HH + hh];
  const float c2 = sigmoidf_(gf)*c0 + sigmoidf_(gi)*tanhf(gg);
  h2t[(size_t)hh*64 + bb] = sigmoidf_(go)*tanhf(c2);
}

// ---------------- K3: head partials; wave = 4 rows x K-half -----------------
// hpart[kc][j][b], kc plane stride 33536
__global__ __launch_bounds__(256) void head_gemm_kernel(
    const float* __restrict__ h2t, const float* __restrict__ Ww,
    const float* __restrict__ Wr, float* __restrict__ hpart)
{
  const int tid = threadIdx.x;
  const int lane = tid & 63;
  const int gw = __builtin_amdgcn_readfirstlane(blockIdx.x*4 + (tid >> 6)); // 264 waves
  const int jg = gw >> 1, kc = gw & 1;
  if (jg >= 131) return;
  const int j0 = jg << 2;
  const float* w0 = (j0+0 < 390) ? (Ww + (size_t)(j0+0)*HH) : (Wr + (size_t)(j0+0-390)*HH);
  const float* w1 = (j0+1 < 390) ? (Ww + (size_t)(j0+1)*HH) : (Wr + (size_t)(j0+1-390)*HH);
  const float* w2 = (j0+2 < 390) ? (Ww + (size_t)(j0+2)*HH) : (Wr + (size_t)(j0+2-390)*HH);
  const float* w3 = (j0+3 < 390) ? (Ww + (size_t)(j0+3)*HH) : (Wr + (size_t)(j0+3-390)*HH);
  const int k0 = kc << 8;
  float a0=0.f, a1=0.f, a2=0.f, a3=0.f;
  #pragma unroll 4
  for (int k = k0; k < k0+256; ++k){
    const float xv = h2t[(size_t)k*64 + lane];
    a0 = fmaf(w0[k],xv,a0); a1 = fmaf(w1[k],xv,a1);
    a2 = fmaf(w2[k],xv,a2); a3 = fmaf(w3[k],xv,a3);
  }
  float* hp = hpart + (size_t)kc*33536 + (size_t)j0*64 + lane;
  hp[0] = a0; hp[64] = a1; hp[128] = a2; hp[192] = a3;
}

// ---------------- K4: interpret heads -> params[b] -------------------------
// params stride 544: [0:128] kwE, [128:256] krE, [256:384] a, [384:512] e,
// 512+: {beta_w,g_w,sw0,sw1,sw2,r_w, beta_r,g_r,sr0,sr1,sr2,r_r, nkw,nkr,C_akr,Ca2}
__global__ void interpret_kernel(const float* __restrict__ hp,
                                 const float* __restrict__ bw,
                                 const float* __restrict__ br,
                                 float* __restrict__ params)
{
  const int b = blockIdx.x, l = threadIdx.x;   // 64 threads
  float* P = params + (size_t)b*544;
  #define OC(j) (hp[(size_t)(j)*64+b] + hp[(size_t)33536+(size_t)(j)*64+b])
  float skw = 0.f, skr = 0.f, sakr = 0.f, sa2 = 0.f;
  #pragma unroll
  for (int f = l; f < 128; f += 64){
    float kwE = OC(f) + bw[f] + EPSF;
    float ee  = sigmoidf_(OC(134+f) + bw[134+f]);
    float aa  = OC(262+f) + bw[262+f];
    float krE = OC(390+f) + br[f] + EPSF;
    P[f] = kwE; P[128+f] = krE; P[256+f] = aa; P[384+f] = ee;
    skw = fmaf(kwE,kwE,skw); skr = fmaf(krE,krE,skr);
    sakr = fmaf(aa,krE,sakr); sa2 = fmaf(aa,aa,sa2);
  }
  #pragma unroll
  for (int m = 32; m >= 1; m >>= 1){
    skw += __shfl_xor(skw,m); skr += __shfl_xor(skr,m);
    sakr += __shfl_xor(sakr,m); sa2 += __shfl_xor(sa2,m);
  }
  if (l == 0){
    P[512+0] = softplusf_(OC(128) + bw[128]);
    P[512+1] = sigmoidf_(OC(129) + bw[129]);
    {
      float x0 = OC(130)+bw[130], x1 = OC(131)+bw[131], x2 = OC(132)+bw[132];
      float mm = fmaxf(x0, fmaxf(x1, x2));
      float e0 = __expf(x0-mm), e1 = __expf(x1-mm), e2 = __expf(x2-mm);
      float s = e0+e1+e2;
      P[512+2] = e0/s; P[512+3] = e1/s; P[512+4] = e2/s;
    }
    P[512+5] = 1.f + softplusf_(OC(133) + bw[133]);
    P[512+6] = softplusf_(OC(518) + br[128]);
    P[512+7] = sigmoidf_(OC(519) + br[129]);
    {
      float x0 = OC(520)+br[130], x1 = OC(521)+br[131], x2 = OC(522)+br[132];
      float mm = fmaxf(x0, fmaxf(x1, x2));
      float e0 = __expf(x0-mm), e1 = __expf(x1-mm), e2 = __expf(x2-mm);
      float s = e0+e1+e2;
      P[512+8] = e0/s; P[512+9] = e1/s; P[512+10] = e2/s;
    }
    P[512+11] = 1.f + softplusf_(OC(523) + br[133]);
    P[512+12] = sqrtf(skw); P[512+13] = sqrtf(skr);
    P[512+14] = sakr;       P[512+15] = sa2;
  }
  #undef OC
}

// ---------------- K5: big pass A — per-row scalars over bank ---------------
// per row: zw = beta_w*cos-sim ; q4 = {S2, S3, C_akr-S4, S5-S6} ; q1 = Ca2-2S7+S8
// Permuted lane->element map; it-loop unrolled x2 (R12 best configuration).
__global__ __launch_bounds__(256) void pass_a_kernel(
    const float* __restrict__ bank, const float* __restrict__ params,
    float* __restrict__ zw, float4* __restrict__ q4, float* __restrict__ q1)
{
  const int blk = blockIdx.x;            // 2048 = 64 b * 32 chunks
  const int b = blk >> 5, chunk = blk & 31;
  const int tid = threadIdx.x;
  const int wv = tid >> 6, lane = tid & 63;
  const int fslot = lane & 7, rsub = lane >> 3;   // 8 lanes per row
  const float* P = params + (size_t)b*544;
  float kw[16], kr[16], av[16], ev[16];
  #pragma unroll
  for (int i = 0; i < 4; ++i){
    #pragma unroll
    for (int j = 0; j < 4; ++j){
      const int idx = 32*i + 4*fslot + j;
      kw[4*i+j] = P[idx];     kr[4*i+j] = P[128+idx];
      av[4*i+j] = P[256+idx]; ev[4*i+j] = P[384+idx];
    }
  }
  const float beta_w = P[512+0], nkw = P[512+12];
  const float C_akr = P[512+14], Ca2 = P[512+15];
  const int eoff = 4*fslot;   // float offset of load i: 32*i + eoff

  #pragma unroll 2
  for (int it = 0; it < 8; it += 2){
    const int n0 = (chunk << 8) + (it << 5) + (wv << 3) + rsub;
    const size_t rowA = (size_t)b*NN + n0;
    const size_t rowB = rowA + 32;
    const float* pA = bank + rowA*FF + eoff;
    const float* pB = bank + rowB*FF + eoff;
    float va[16], vb[16];
    #pragma unroll
    for (int i = 0; i < 4; ++i)
      *reinterpret_cast<float4*>(&va[4*i]) = *reinterpret_cast<const float4*>(pA + 32*i);
    #pragma unroll
    for (int i = 0; i < 4; ++i)
      *reinterpret_cast<float4*>(&vb[4*i]) = *reinterpret_cast<const float4*>(pB + 32*i);

    #pragma unroll
    for (int half = 0; half < 2; ++half){
      const float* mv = (half == 0) ? va : vb;
      const size_t row = (half == 0) ? rowA : rowB;
      float s1=0.f,s2=0.f,s3=0.f,s4=0.f,s5=0.f,s6=0.f,s7=0.f,s8=0.f;
      #pragma unroll
      for (int i = 0; i < 16; ++i){
        const float m = mv[i], u = m + EPSF, em = ev[i]*m;
        s1 = fmaf(u,kw[i],s1);  s2 = fmaf(u,u,s2);
        s3 = fmaf(u,kr[i],s3);  s4 = fmaf(em,kr[i],s4);
        s5 = fmaf(u,av[i],s5);  s6 = fmaf(u,em,s6);
        s7 = fmaf(av[i],em,s7); s8 = fmaf(em,em,s8);
      }
      #pragma unroll
      for (int mm = 1; mm < 8; mm <<= 1){
        s1 += __shfl_xor(s1,mm); s2 += __shfl_xor(s2,mm);
        s3 += __shfl_xor(s3,mm); s4 += __shfl_xor(s4,mm);
        s5 += __shfl_xor(s5,mm); s6 += __shfl_xor(s6,mm);
        s7 += __shfl_xor(s7,mm); s8 += __shfl_xor(s8,mm);
      }
      if (fslot == 0){
        const float sim = s1 / fmaxf(sqrtf(s2)*nkw, 1e-8f);
        zw[row] = beta_w * sim;
        q4[row] = make_float4(s2, s3, C_akr - s4, s5 - s6);
        q1[row] = Ca2 - 2.f*s7 + s8;
      }
    }
  }
}

// ---------------- 2-sync block reductions for K6 (1024 thr = 16 waves) -----
__device__ __forceinline__ float blockMaxF(float v, float* red, int tid){
  #pragma unroll
  for (int m = 32; m >= 1; m >>= 1) v = fmaxf(v, __shfl_xor(v,m));
  if ((tid & 63) == 0) red[tid >> 6] = v;
  __syncthreads();
  if (tid < 64){
    float x = (tid < 16) ? red[tid] : -1e30f;
    #pragma unroll
    for (int m = 8; m >= 1; m >>= 1) x = fmaxf(x, __shfl_xor(x,m));
    if (tid == 0) red[16] = x;
  }
  __syncthreads();
  return red[16];
}
__device__ __forceinline__ float blockSumF(float v, float* red, int tid){
  #pragma unroll
  for (int m = 32; m >= 1; m >>= 1) v += __shfl_xor(v,m);
  if ((tid & 63) == 0) red[tid >> 6] = v;
  __syncthreads();
  if (tid < 64){
    float x = (tid < 16) ? red[tid] : 0.f;
    #pragma unroll
    for (int m = 8; m >= 1; m >>= 1) x += __shfl_xor(x,m);
    if (tid == 0) red[16] = x;
  }
  __syncthreads();
  return red[16];
}

// ---------------- K6: per-batch softmax/conv/sharpen pipeline x2 -----------
// All global loads hoisted to entry; sharpen results kept in registers.
__global__ __launch_bounds__(1024) void head_pipeline_kernel(
    const float* __restrict__ zw, const float4* __restrict__ q4,
    const float* __restrict__ q1,
    const float* __restrict__ w_write, const float* __restrict__ w_read,
    const float* __restrict__ params,
    float* __restrict__ wrg, float* __restrict__ wrwwg, float* __restrict__ T3g)
{
  __shared__ float wa[NN];
  __shared__ float red[20];
  const int b = blockIdx.x;
  const int tid = threadIdx.x;
  const float* P = params + (size_t)b*544 + 512;
  const float g_w = P[1], sw0 = P[2], sw1 = P[3], sw2 = P[4], r_w = P[5];
  const float beta_r = P[6], g_r = P[7], sr0 = P[8], sr1 = P[9], sr2 = P[10], r_r = P[11];
  const float nkr = P[13];
  const size_t base = (size_t)b*NN;

  // ---- hoist ALL global loads (latency paid once, overlapped) ----
  float  zv[8], q1v[8], wwr[8], wrd[8];
  float4 qv[8];
  #pragma unroll
  for (int i = 0; i < 8; ++i){ int n = tid + (i<<10); zv[i]  = zw[base+n]; }
  #pragma unroll
  for (int i = 0; i < 8; ++i){ int n = tid + (i<<10); qv[i]  = q4[base+n]; }
  #pragma unroll
  for (int i = 0; i < 8; ++i){ int n = tid + (i<<10); q1v[i] = q1[base+n]; }
  #pragma unroll
  for (int i = 0; i < 8; ++i){ int n = tid + (i<<10); wwr[i] = w_write[base+n]; }
  #pragma unroll
  for (int i = 0; i < 8; ++i){ int n = tid + (i<<10); wrd[i] = w_read[base+n]; }

  float cv[8], wwv[8];

  // ======== write head ========
  float lm = -1e30f;
  #pragma unroll
  for (int i = 0; i < 8; ++i) lm = fmaxf(lm, zv[i]);
  float M = blockMaxF(lm, red, tid);
  float ls = 0.f;
  #pragma unroll
  for (int i = 0; i < 8; ++i){ zv[i] = __expf(zv[i]-M); ls += zv[i]; }
  float S = blockSumF(ls, red, tid);
  const float invS = 1.f/S;
  #pragma unroll
  for (int i = 0; i < 8; ++i){ int n = tid + (i<<10); wa[n] = zv[i]*invS + (1.f-g_w)*wwr[i]; }
  __syncthreads();
  #pragma unroll
  for (int i = 0; i < 8; ++i){ int n = tid + (i<<10);
    cv[i] = sw0*wa[(n+NN-1)&(NN-1)] + sw1*wa[n] + sw2*wa[(n+1)&(NN-1)]; }
  __syncthreads();
  float lp = 0.f;
  #pragma unroll
  for (int i = 0; i < 8; ++i){ cv[i] = __expf(r_w*__logf(cv[i])); lp += cv[i]; }
  float Sp = blockSumF(lp, red, tid);
  float inv = 1.f/(Sp + EPSF);
  #pragma unroll
  for (int i = 0; i < 8; ++i) wwv[i] = cv[i]*inv;

  // ======== read head (bank2 stats reconstructed from qv/q1v + ww) ========
  lm = -1e30f;
  #pragma unroll
  for (int i = 0; i < 8; ++i){
    const float ww = wwv[i];
    const float num = qv[i].y + ww*qv[i].z;
    const float d2  = qv[i].x + 2.f*ww*qv[i].w + ww*ww*q1v[i];
    const float den = sqrtf(d2)*nkr;
    zv[i] = beta_r * (num / fmaxf(den, 1e-8f));
    lm = fmaxf(lm, zv[i]);
  }
  M = blockMaxF(lm, red, tid);
  ls = 0.f;
  #pragma unroll
  for (int i = 0; i < 8; ++i){ zv[i] = __expf(zv[i]-M); ls += zv[i]; }
  S = blockSumF(ls, red, tid);
  const float invS2 = 1.f/S;
  #pragma unroll
  for (int i = 0; i < 8; ++i){ int n = tid + (i<<10); wa[n] = zv[i]*invS2 + (1.f-g_r)*wrd[i]; }
  __syncthreads();
  #pragma unroll
  for (int i = 0; i < 8; ++i){ int n = tid + (i<<10);
    cv[i] = sr0*wa[(n+NN-1)&(NN-1)] + sr1*wa[n] + sr2*wa[(n+1)&(NN-1)]; }
  __syncthreads();
  float lp2 = 0.f;
  #pragma unroll
  for (int i = 0; i < 8; ++i){ cv[i] = __expf(r_r*__logf(cv[i])); lp2 += cv[i]; }
  float Sp2 = blockSumF(lp2, red, tid);
  inv = 1.f/(Sp2 + EPSF);
  float t3 = 0.f;
  #pragma unroll
  for (int i = 0; i < 8; ++i){
    int n = tid + (i<<10);
    const float wr_ = cv[i]*inv;
    wrg[base+n] = wr_;
    const float xx = wr_*wwv[i];
    wrwwg[base+n] = xx;
    t3 += xx;
  }
  float T3 = blockSumF(t3, red, tid);
  if (tid == 0) T3g[b] = T3;
}

// ---------------- K7: big pass D — weighted reductions over bank -----------
// REVERSED traversal (L3-resident tail first); unrolled x8 for MLP.
__global__ __launch_bounds__(256) void pass_d_kernel(
    const float* __restrict__ bank, const float* __restrict__ wrg,
    const float* __restrict__ wrwwg, float* __restrict__ pT)
{
  const int blk = 2047 - blockIdx.x;    // 2048 = 64 b * 32 chunks, reversed
  const int b = blk >> 5, chunk = blk & 31;
  const int tid = threadIdx.x;
  const int st = tid >> 5, li = tid & 31;   // 8 row-streams, 32 f4 each
  float4 a1 = make_float4(0.f,0.f,0.f,0.f);
  float4 a2 = make_float4(0.f,0.f,0.f,0.f);
  for (int it = 24; it >= 0; it -= 8){
    float w1v[8], w2v[8];
    float4 mv[8];
    #pragma unroll
    for (int u = 0; u < 8; ++u){
      const int n = (chunk << 8) + ((it+u) << 3) + st;
      const size_t row = (size_t)b*NN + n;
      w1v[u] = wrg[row];
      w2v[u] = wrwwg[row];
      mv[u] = reinterpret_cast<const float4*>(bank + row*FF)[li];
    }
    #pragma unroll
    for (int u = 0; u < 8; ++u){
      a1.x = fmaf(w1v[u],mv[u].x,a1.x); a1.y = fmaf(w1v[u],mv[u].y,a1.y);
      a1.z = fmaf(w1v[u],mv[u].z,a1.z); a1.w = fmaf(w1v[u],mv[u].w,a1.w);
      a2.x = fmaf(w2v[u],mv[u].x,a2.x); a2.y = fmaf(w2v[u],mv[u].y,a2.y);
      a2.z = fmaf(w2v[u],mv[u].z,a2.z); a2.w = fmaf(w2v[u],mv[u].w,a2.w);
    }
  }
  __shared__ float lds[8*256];
  *reinterpret_cast<float4*>(&lds[st*256 + li*4]) = a1;
  *reinterpret_cast<float4*>(&lds[st*256 + 128 + li*4]) = a2;
  __syncthreads();
  float s = 0.f;
  #pragma unroll
  for (int k = 0; k < 8; ++k) s += lds[k*256 + tid];
  pT[(size_t)blk*256 + tid] = s;
}

// ---------------- K7b: reduce partials -> rvec ------------------------------
__global__ __launch_bounds__(256) void rvec_kernel(
    const float* __restrict__ pT, const float* __restrict__ params,
    const float* __restrict__ T3g, float* __restrict__ rvec)
{
  const int gid = blockIdx.x*256 + threadIdx.x;   // 8192
  const int b = gid >> 7, f = gid & 127;
  float t1 = 0.f, t2 = 0.f;
  for (int cc = 0; cc < 32; ++cc){
    const float* p = pT + (size_t)((b<<5) + cc)*256;
    t1 += p[f]; t2 += p[128+f];
  }
  const float* P = params + (size_t)b*544;
  rvec[gid] = t1 - P[384+f]*t2 + P[256+f]*T3g[b];
}

// ---------------- K8: out = rvec @ W_out^T + b_out --------------------------
__global__ __launch_bounds__(256) void out_gemm_kernel(
    const float* __restrict__ rvec, const float* __restrict__ Wout,
    const float* __restrict__ bout, float* __restrict__ out)
{
  const int tid = threadIdx.x;
  const int wv = __builtin_amdgcn_readfirstlane(tid >> 6);
  const int lane = tid & 63;     // lane = batch
  const int j0 = blockIdx.x*32 + wv*8;
  float acc[8];
  #pragma unroll
  for (int jj = 0; jj < 8; ++jj){ int j = j0 + jj; acc[jj] = (j < VV) ? bout[j] : 0.f; }
  for (int fc = 0; fc < 128; fc += 32){
    float rv[32];
    #pragma unroll
    for (int i = 0; i < 32; ++i) rv[i] = rvec[lane*128 + fc + i];
    #pragma unroll
    for (int jj = 0; jj < 8; ++jj){
      const int j = j0 + jj;
      if (j < VV){
        const float* w = Wout + (size_t)j*128 + fc;
        #pragma unroll
        for (int i = 0; i < 32; ++i) acc[jj] = fmaf(w[i], rv[i], acc[jj]);
      }
    }
  }
  #pragma unroll
  for (int jj = 0; jj < 8; ++jj){
    int j = j0 + jj;
    if (j < VV) out[(size_t)lane*VV + j] = acc[jj];
  }
}

// ---------------------------------------------------------------------------
extern "C" void kernel_launch(void* const* d_in, const int* in_sizes, int n_in,
                              void* d_out, int out_size, void* d_ws, size_t ws_size,
                              hipStream_t stream)
{
  const int*   x       = (const int*)  d_in[0];
  const float* h       = (const float*)d_in[1];
  const float* c       = (const float*)d_in[2];
  const float* w_read  = (const float*)d_in[3];
  const float* w_write = (const float*)d_in[4];
  const float* bank    = (const float*)d_in[5];
  const float* emb     = (const float*)d_in[6];
  const float* Wih     = (const float*)d_in[7];
  const float* bih     = (const float*)d_in[8];
  const float* Whh     = (const float*)d_in[9];
  const float* bhh     = (const float*)d_in[10];
  const float* Wr      = (const float*)d_in[11];
  const float* br      = (const float*)d_in[12];
  const float* Ww      = (const float*)d_in[13];
  const float* bw      = (const float*)d_in[14];
  const float* Wout    = (const float*)d_in[15];
  const float* bout    = (const float*)d_in[16];
  float* out = (float*)d_out;
  float* ws  = (float*)d_ws;

  float* Xt    = ws + OFF_XT;
  float* gpart = ws + OFF_GPART;
  float* h2t   = ws + OFF_H2T;
  float* hpart = ws + OFF_HPART;
  float* par   = ws + OFF_PAR;
  float* zwp   = ws + OFF_ZW;
  float4* q4p  = reinterpret_cast<float4*>(ws + OFF_Q4);
  float* q1p   = ws + OFF_Q1;
  float* wrp   = ws + OFF_WR;
  float* wrwwp = ws + OFF_WRWW;
  float* pTp   = ws + OFF_PT;
  float* T3p   = ws + OFF_T3;
  float* rvp   = ws + OFF_RVEC;

  hipLaunchKernelGGL(gather_xt_kernel,     dim3(192),  dim3(256), 0, stream, x, h, emb, Xt);
  hipLaunchKernelGGL(lstm_gates_kernel,    dim3(256),  dim3(256), 0, stream, Xt, Wih, Whh, gpart);
  hipLaunchKernelGGL(lstm_act_kernel,      dim3(128),  dim3(256), 0, stream, gpart, bih, bhh, c, h2t);
  hipLaunchKernelGGL(head_gemm_kernel,     dim3(66),   dim3(256), 0, stream, h2t, Ww, Wr, hpart);
  hipLaunchKernelGGL(interpret_kernel,     dim3(64),   dim3(64),  0, stream, hpart, bw, br, par);
  hipLaunchKernelGGL(pass_a_kernel,        dim3(2048), dim3(256), 0, stream, bank, par, zwp, q4p, q1p);
  hipLaunchKernelGGL(head_pipeline_kernel, dim3(64),   dim3(1024),0, stream, zwp, q4p, q1p, w_write, w_read, par, wrp, wrwwp, T3p);
  hipLaunchKernelGGL(pass_d_kernel,        dim3(2048), dim3(256), 0, stream, bank, wrp, wrwwp, pTp);
  hipLaunchKernelGGL(rvec_kernel,          dim3(32),   dim3(256), 0, stream, pTp, par, T3p, rvp);
  hipLaunchKernelGGL(out_gemm_kernel,      dim3(313),  dim3(256), 0, stream, rvp, Wout, bout, out);
}